// Round 9
// baseline (575.401 us; speedup 1.0000x reference)
//
#include <hip/hip_runtime.h>
#include <stdint.h>
#include <math.h>

#define NB 2
#define SS 2048
#define HH 2048
#define NHH 32
#define HDD 64
#define MM (NB*SS)   // 4096

typedef __attribute__((ext_vector_type(8))) short short8;
typedef __attribute__((ext_vector_type(4))) short short4v;
typedef __attribute__((ext_vector_type(4))) float f32x4;

#define GLOBAL_AS const __attribute__((address_space(1))) void*
#define LDS_AS __attribute__((address_space(3))) void*

static __device__ __forceinline__ short rne_bf16(float x) {
    uint32_t u = __builtin_bit_cast(uint32_t, x);
    u += 0x7FFFu + ((u >> 16) & 1u);
    return (short)(u >> 16);
}
static __device__ __forceinline__ float bf16f(short h) {
    return __builtin_bit_cast(float, (uint32_t)((uint16_t)h) << 16);
}
// HW packed f32->bf16 (RNE), gfx950: lo16 = bf16(a), hi16 = bf16(b)
static __device__ __forceinline__ uint32_t cvt_pk_bf16(float a, float b) {
    uint32_t r;
    asm("v_cvt_pk_bf16_f32 %0, %1, %2" : "=v"(r) : "v"(a), "v"(b));
    return r;
}
static __device__ __forceinline__ float fast_exp2(float x) {
    float r;
    asm("v_exp_f32 %0, %1" : "=v"(r) : "v"(x));
    return r;
}

// ---------------- fused convert: X, Wq, Wk, Wv (plain) + Wo (split) ----------------
#define N4X  2097152   // MM*HH/4
#define N4W  1048576   // HH*HH/4
__global__ void __launch_bounds__(256)
k_cvt_all(const float* __restrict__ X, const float* __restrict__ Wq,
          const float* __restrict__ Wk, const float* __restrict__ Wv,
          const float* __restrict__ Wo,
          short* __restrict__ Xh, short* __restrict__ Wqh, short* __restrict__ Wkh,
          short* __restrict__ Wvh, short* __restrict__ Woh, short* __restrict__ Wol)
{
    int i = blockIdx.x * blockDim.x + threadIdx.x;
    const float* src;
    short* dst;
    int j = i;
    if (i < N4X)                { src = X;  dst = Xh;  }
    else if (i < N4X + N4W)     { src = Wq; dst = Wqh; j = i - N4X; }
    else if (i < N4X + 2*N4W)   { src = Wk; dst = Wkh; j = i - N4X - N4W; }
    else if (i < N4X + 3*N4W)   { src = Wv; dst = Wvh; j = i - N4X - 2*N4W; }
    else {
        j = i - N4X - 3*N4W;
        float4 f = reinterpret_cast<const float4*>(Wo)[j];
        short4v h, l;
        h.x = rne_bf16(f.x); l.x = rne_bf16(f.x - bf16f(h.x));
        h.y = rne_bf16(f.y); l.y = rne_bf16(f.y - bf16f(h.y));
        h.z = rne_bf16(f.z); l.z = rne_bf16(f.z - bf16f(h.z));
        h.w = rne_bf16(f.w); l.w = rne_bf16(f.w - bf16f(h.w));
        reinterpret_cast<short4v*>(Woh)[j] = h;
        reinterpret_cast<short4v*>(Wol)[j] = l;
        return;
    }
    float4 f = reinterpret_cast<const float4*>(src)[j];
    short4v o;
    o.x = rne_bf16(f.x); o.y = rne_bf16(f.y);
    o.z = rne_bf16(f.z); o.w = rne_bf16(f.w);
    reinterpret_cast<short4v*>(dst)[j] = o;
}

// ---------------- fused QKV projection GEMM + RoPE ----------------
// Only A staged in LDS (round-4 BK=64 structure + verified swizzle);
// B fragments (Wq/Wk/Wv) read DIRECTLY from global/L2 — identical bytes and
// fragment layout as the old LDS path, but LDS traffic per CU-step drops
// 384->96 KB (LDS pipe was the ~61us co-floor; B panels are 3MB, L2-resident
// per XCD via the T1 remap). Sync structure identical to round 4.
__global__ void __launch_bounds__(256, 2)
k_gemm_qkv(const short* __restrict__ X,
           const short* __restrict__ Wqh, const short* __restrict__ Wkh, const short* __restrict__ Wvh,
           const float* __restrict__ cosT, const float* __restrict__ sinT,
           short* __restrict__ Qr, short* __restrict__ Kr, short* __restrict__ Vt)
{
    __shared__ short lA[128 * 64];   // 16 KB, A tile only
    const int tid = threadIdx.x;
    const int lane = tid & 63;
    const int wave = tid >> 6;
    const int lrow = lane & 15;
    const int quad = lane >> 4;
    const int swz = lrow & 7;

    // XCD-chunked remap: lin%8 = XCD; each XCD gets nblk in {2x,2x+1} x all mblk
    const int lin = blockIdx.y * 16 + blockIdx.x;   // grid (16,32)
    const int pos = lin >> 3;
    const int nblk = ((lin & 7) * 2 + (pos & 1)) * 128;
    const int mblk = (pos >> 1) * 128;
    const int m0 = mblk + (wave >> 1) * 64;
    const int n0 = nblk + (wave & 1) * 64;
    const int mw = (wave >> 1) * 64;
    const int nw = (wave & 1) * 64;

    // A staging (round-4 pattern): wave w, call j covers rows w*32 + j*8 + (lane>>3);
    // 16B chunk (lane&7)^(lane>>3) of the 128B row (inverse swizzle at source).
    const int srow = wave * 32 + (lane >> 3);
    const int skc = ((lane & 7) ^ (lane >> 3)) * 8;
    const short* gA = X + (size_t)(mblk + srow) * HH + skc;
    const int lofs = wave * 2048;

    // B fragment base pointers (per z, per nt): row = nblk + nw + nt*16 + lrow
    const short* Wz3[3] = { Wqh, Wkh, Wvh };
    const short* bp[3][4];
    #pragma unroll
    for (int z = 0; z < 3; z++)
        #pragma unroll
        for (int nt = 0; nt < 4; nt++)
            bp[z][nt] = Wz3[z] + (size_t)(nblk + nw + nt * 16 + lrow) * HH + quad * 8;

    f32x4 acc[3][4][4];
    #pragma unroll
    for (int z = 0; z < 3; z++)
        #pragma unroll
        for (int i = 0; i < 4; i++)
            #pragma unroll
            for (int j = 0; j < 4; j++) acc[z][i][j] = 0.f;

    #pragma unroll 1
    for (int k0 = 0; k0 < HH; k0 += 64) {
        __syncthreads();
        #pragma unroll
        for (int j = 0; j < 4; j++)
            __builtin_amdgcn_global_load_lds((GLOBAL_AS)(gA + (size_t)j * 8 * HH + k0),
                                             (LDS_AS)(&lA[lofs + j * 512]), 16, 0, 0);
        __syncthreads();

        #pragma unroll
        for (int kk = 0; kk < 2; kk++) {
            const int csl = ((kk * 4 + quad) ^ swz) * 8;
            short8 a[4];
            #pragma unroll
            for (int mt = 0; mt < 4; mt++)
                a[mt] = *reinterpret_cast<const short8*>(&lA[(mw + mt * 16 + lrow) * 64 + csl]);
            #pragma unroll
            for (int z = 0; z < 3; z++) {
                short8 b[4];
                #pragma unroll
                for (int nt = 0; nt < 4; nt++)
                    b[nt] = *reinterpret_cast<const short8*>(bp[z][nt] + k0 + kk * 32);
                #pragma unroll
                for (int mt = 0; mt < 4; mt++)
                    #pragma unroll
                    for (int nt = 0; nt < 4; nt++)
                        acc[z][mt][nt] = __builtin_amdgcn_mfma_f32_16x16x32_bf16(a[mt], b[nt], acc[z][mt][nt], 0, 0, 0);
            }
        }
    }

    const float QSCL = 0.18033688011112042f;  // log2(e)/sqrt(HD)

    #pragma unroll
    for (int z = 0; z < 3; z++) {
        #pragma unroll
        for (int mt = 0; mt < 4; mt++) {
            #pragma unroll
            for (int r = 0; r < 4; r++) {
                int row = m0 + mt * 16 + quad * 4 + r;   // global m = b*S + s
                int b_i = row >> 11;
                int s_i = row & (SS - 1);
                #pragma unroll
                for (int nt = 0; nt < 4; nt++) {
                    int col = n0 + nt * 16 + lrow;       // global n = h*64 + d
                    int h_i = col >> 6;
                    int d_i = col & 63;
                    float v = acc[z][mt][nt][r];
                    if (z < 2) {
                        float pair = (nt & 2) ? acc[z][mt][nt - 2][r] : -acc[z][mt][nt + 2][r];
                        float c = cosT[s_i * HDD + d_i];
                        float sn = sinT[s_i * HDD + d_i];
                        v = v * c + pair * sn;
                        if (z == 0) v *= QSCL;
                        short* dst = (z == 0) ? Qr : Kr;
                        dst[(((size_t)b_i * NHH + h_i) * SS + s_i) * HDD + d_i] = rne_bf16(v);
                    } else {
                        Vt[(((size_t)b_i * NHH + h_i) * HDD + d_i) * SS + s_i] = rne_bf16(v);
                    }
                }
            }
        }
    }
}

// ---------------- flash attention: S^T MFMA + fixed-max softmax ----------------
// (unchanged from round 4: LDS-shared K/V dbuf, cvt_pk pack, MFMA-ones denom)
__global__ void __launch_bounds__(256, 2)
k_attn(const short* __restrict__ Qr, const short* __restrict__ Kr, const short* __restrict__ Vt,
       const float* __restrict__ mask,
       short* __restrict__ Ah, short* __restrict__ Al)
{
    __shared__ short plds[4][4096];    // 32 KB: per-wave P scratch (swizzled)
    __shared__ short ldsK[2][4096];    // 16 KB: K tile dbuf, 64 rows x 64 d, xor-swizzled
    __shared__ short ldsV[2][4096];    // 16 KB: V tile dbuf, 64 d x 64 k, xor-swizzled
    const int lane = threadIdx.x & 63;
    const int wave = threadIdx.x >> 6;
    const int lrow = lane & 15;
    const int quad = lane >> 4;
    const int aofs = lrow & 7;
    const int b = blockIdx.x >> 5;
    const int h = blockIdx.x & 31;
    const int q0w = blockIdx.y * 256 + wave * 64;

    const size_t bh = (size_t)b * NHH + h;
    const short* Qbase = Qr + bh * SS * HDD;
    const short* Kbase = Kr + bh * SS * HDD;
    const short* Vbase = Vt + bh * (size_t)HDD * SS;
    const float* mrow = mask + b * SS;
    char* cb = (char*)&plds[wave][0];

    const int strow = lane >> 3;                 // 0..7
    const int stch  = (lane & 7) ^ strow;        // pre-swizzled chunk
    const short* Kst0 = Kbase + (size_t)(wave * 16 + strow)     * HDD + stch * 8;
    const short* Kst1 = Kbase + (size_t)(wave * 16 + 8 + strow) * HDD + stch * 8;
    const short* Vst0 = Vbase + (size_t)(wave * 16 + strow)     * SS  + stch * 8;
    const short* Vst1 = Vbase + (size_t)(wave * 16 + 8 + strow) * SS  + stch * 8;
    const int ldst0 = wave * 1024;       // shorts: rows w*16 .. w*16+7
    const int ldst1 = wave * 1024 + 512; // shorts: rows w*16+8 .. w*16+15

#define STAGE_KV(buf, kk) do { \
    __builtin_amdgcn_global_load_lds((GLOBAL_AS)(Kst0 + (size_t)(kk) * HDD), (LDS_AS)(&ldsK[buf][ldst0]), 16, 0, 0); \
    __builtin_amdgcn_global_load_lds((GLOBAL_AS)(Kst1 + (size_t)(kk) * HDD), (LDS_AS)(&ldsK[buf][ldst1]), 16, 0, 0); \
    __builtin_amdgcn_global_load_lds((GLOBAL_AS)(Vst0 + (kk)), (LDS_AS)(&ldsV[buf][ldst0]), 16, 0, 0); \
    __builtin_amdgcn_global_load_lds((GLOBAL_AS)(Vst1 + (kk)), (LDS_AS)(&ldsV[buf][ldst1]), 16, 0, 0); \
} while (0)

    short8 qf[4][2];
    #pragma unroll
    for (int nt = 0; nt < 4; nt++)
        #pragma unroll
        for (int c = 0; c < 2; c++)
            qf[nt][c] = *reinterpret_cast<const short8*>(
                Qbase + (size_t)(q0w + nt * 16 + lrow) * HDD + c * 32 + quad * 8);

    short8 onesf;
    #pragma unroll
    for (int i = 0; i < 8; i++) onesf[i] = (short)0x3F80;   // bf16 1.0

    f32x4 oacc[4][4];
    f32x4 lacc[4];
    #pragma unroll
    for (int i = 0; i < 4; i++) {
        lacc[i] = 0.f;
        #pragma unroll
        for (int j = 0; j < 4; j++) oacc[i][j] = 0.f;
    }

    const float L2E = 1.44269504f;

    // prologue: stage tile 0
    STAGE_KV(0, 0);
    asm volatile("s_waitcnt vmcnt(0)" ::: "memory");
    __syncthreads();

    int cur = 0;
    #pragma unroll 1
    for (int k0 = 0; k0 < SS; k0 += 64) {
        if (k0 + 64 < SS) STAGE_KV(cur ^ 1, k0 + 64);

        short8 kf[4][2];
        #pragma unroll
        for (int kt = 0; kt < 4; kt++)
            #pragma unroll
            for (int c = 0; c < 2; c++)
                kf[kt][c] = *reinterpret_cast<const short8*>(
                    &ldsK[cur][(kt * 16 + lrow) * 64 + (((4 * c + quad) ^ aofs) * 8)]);

        f32x4 sacc[4][4];
        #pragma unroll
        for (int kt = 0; kt < 4; kt++)
            #pragma unroll
            for (int nt = 0; nt < 4; nt++) {
                f32x4 z4 = 0.f;
                z4 = __builtin_amdgcn_mfma_f32_16x16x32_bf16(kf[kt][0], qf[nt][0], z4, 0, 0, 0);
                sacc[kt][nt] = __builtin_amdgcn_mfma_f32_16x16x32_bf16(kf[kt][1], qf[nt][1], z4, 0, 0, 0);
            }

        asm volatile("s_waitcnt lgkmcnt(0)" ::: "memory");

        #pragma unroll
        for (int kt = 0; kt < 4; kt++) {
            float4 mk = *reinterpret_cast<const float4*>(mrow + k0 + kt * 16 + quad * 4);
            float m0v = mk.x * L2E, m1v = mk.y * L2E, m2v = mk.z * L2E, m3v = mk.w * L2E;
            #pragma unroll
            for (int nt = 0; nt < 4; nt++) {
                float p0 = fast_exp2(sacc[kt][nt][0] + m0v);
                float p1 = fast_exp2(sacc[kt][nt][1] + m1v);
                float p2 = fast_exp2(sacc[kt][nt][2] + m2v);
                float p3 = fast_exp2(sacc[kt][nt][3] + m3v);
                uint2 w;
                w.x = cvt_pk_bf16(p0, p1);
                w.y = cvt_pk_bf16(p2, p3);
                *reinterpret_cast<uint2*>(
                    cb + (nt * 16 + lrow) * 128 +
                    (((2 * kt + (quad >> 1)) ^ aofs) * 16) + (quad & 1) * 8) = w;
            }
        }

        asm volatile("s_waitcnt lgkmcnt(0)" ::: "memory");

        #pragma unroll
        for (int c = 0; c < 2; c++) {
            short8 pf[4], vf[4];
            #pragma unroll
            for (int mt = 0; mt < 4; mt++)
                pf[mt] = *reinterpret_cast<const short8*>(
                    cb + (mt * 16 + lrow) * 128 + (((4 * c + quad) ^ aofs) * 16));
            #pragma unroll
            for (int dt = 0; dt < 4; dt++)
                vf[dt] = *reinterpret_cast<const short8*>(
                    &ldsV[cur][(dt * 16 + lrow) * 64 + (((4 * c + quad) ^ aofs) * 8)]);
            #pragma unroll
            for (int mt = 0; mt < 4; mt++) {
                lacc[mt] = __builtin_amdgcn_mfma_f32_16x16x32_bf16(pf[mt], onesf, lacc[mt], 0, 0, 0);
                #pragma unroll
                for (int dt = 0; dt < 4; dt++)
                    oacc[mt][dt] = __builtin_amdgcn_mfma_f32_16x16x32_bf16(pf[mt], vf[dt], oacc[mt][dt], 0, 0, 0);
            }
        }

        asm volatile("s_waitcnt vmcnt(0)" ::: "memory");
        __syncthreads();
        cur ^= 1;
    }
#undef STAGE_KV

    float linv[4][4];
    #pragma unroll
    for (int mt = 0; mt < 4; mt++)
        #pragma unroll
        for (int r = 0; r < 4; r++)
            linv[mt][r] = 1.f / lacc[mt][r];

    #pragma unroll
    for (int mt = 0; mt < 4; mt++) {
        #pragma unroll
        for (int r = 0; r < 4; r++) {
            int s_i = q0w + mt * 16 + quad * 4 + r;
            size_t row = (size_t)b * SS + s_i;
            #pragma unroll
            for (int dt = 0; dt < 4; dt++) {
                float x = oacc[mt][dt][r] * linv[mt][r];
                short hi = rne_bf16(x);
                short lo = rne_bf16(x - bf16f(hi));
                size_t idx = row * HH + (size_t)h * 64 + dt * 16 + lrow;
                Ah[idx] = hi;
                Al[idx] = lo;
            }
        }
    }
}

// ---------------- output projection GEMM, split-bf16 (3-term) ----------------
// Ah/Al staged in LDS (round-4 structure); Bh/Bl fragments read directly from
// global/L2 (2MB panel per XCD, L2-resident). LDS traffic 384->192 KB/step.
__global__ void __launch_bounds__(256, 2)
k_gemm_wo(const short* __restrict__ Ahh, const short* __restrict__ All,
          const short* __restrict__ Bhh, const short* __restrict__ Bll,
          float* __restrict__ C)
{
    __shared__ short lAh[128 * 64];
    __shared__ short lAl[128 * 64];
    const int tid = threadIdx.x;
    const int lane = tid & 63;
    const int wave = tid >> 6;
    const int lrow = lane & 15;
    const int quad = lane >> 4;
    const int swz = lrow & 7;

    const int lin = blockIdx.y * 16 + blockIdx.x;   // grid (16,32)
    const int pos = lin >> 3;
    const int nblk = ((lin & 7) * 2 + (pos & 1)) * 128;
    const int mblk = (pos >> 1) * 128;
    const int m0 = mblk + (wave >> 1) * 64;
    const int n0 = nblk + (wave & 1) * 64;
    const int mw = (wave >> 1) * 64;
    const int nw = (wave & 1) * 64;

    const int srow = wave * 32 + (lane >> 3);
    const int skc = ((lane & 7) ^ (lane >> 3)) * 8;
    const short* gAh = Ahh + (size_t)(mblk + srow) * HH + skc;
    const short* gAl = All + (size_t)(mblk + srow) * HH + skc;
    const int lofs = wave * 2048;

    const short* bph[4];
    const short* bpl[4];
    #pragma unroll
    for (int nt = 0; nt < 4; nt++) {
        size_t rofs = (size_t)(nblk + nw + nt * 16 + lrow) * HH + quad * 8;
        bph[nt] = Bhh + rofs;
        bpl[nt] = Bll + rofs;
    }

    f32x4 acc[4][4];
    #pragma unroll
    for (int i = 0; i < 4; i++)
        #pragma unroll
        for (int j = 0; j < 4; j++) acc[i][j] = 0.f;

    #pragma unroll 1
    for (int k0 = 0; k0 < HH; k0 += 64) {
        __syncthreads();
        #pragma unroll
        for (int j = 0; j < 4; j++) {
            size_t go = (size_t)j * 8 * HH + k0;
            __builtin_amdgcn_global_load_lds((GLOBAL_AS)(gAh + go), (LDS_AS)(&lAh[lofs + j * 512]), 16, 0, 0);
            __builtin_amdgcn_global_load_lds((GLOBAL_AS)(gAl + go), (LDS_AS)(&lAl[lofs + j * 512]), 16, 0, 0);
        }
        __syncthreads();

        #pragma unroll
        for (int kk = 0; kk < 2; kk++) {
            const int csl = ((kk * 4 + quad) ^ swz) * 8;
            short8 ah[4], al[4], bh[4], bl[4];
            #pragma unroll
            for (int mt = 0; mt < 4; mt++) {
                int off = (mw + mt * 16 + lrow) * 64 + csl;
                ah[mt] = *reinterpret_cast<const short8*>(&lAh[off]);
                al[mt] = *reinterpret_cast<const short8*>(&lAl[off]);
            }
            #pragma unroll
            for (int nt = 0; nt < 4; nt++) {
                bh[nt] = *reinterpret_cast<const short8*>(bph[nt] + k0 + kk * 32);
                bl[nt] = *reinterpret_cast<const short8*>(bpl[nt] + k0 + kk * 32);
            }
            #pragma unroll
            for (int mt = 0; mt < 4; mt++)
                #pragma unroll
                for (int nt = 0; nt < 4; nt++) {
                    acc[mt][nt] = __builtin_amdgcn_mfma_f32_16x16x32_bf16(ah[mt], bh[nt], acc[mt][nt], 0, 0, 0);
                    acc[mt][nt] = __builtin_amdgcn_mfma_f32_16x16x32_bf16(al[mt], bh[nt], acc[mt][nt], 0, 0, 0);
                    acc[mt][nt] = __builtin_amdgcn_mfma_f32_16x16x32_bf16(ah[mt], bl[nt], acc[mt][nt], 0, 0, 0);
                }
        }
    }

    #pragma unroll
    for (int mt = 0; mt < 4; mt++)
        #pragma unroll
        for (int r = 0; r < 4; r++) {
            int row = m0 + mt * 16 + quad * 4 + r;
            #pragma unroll
            for (int nt = 0; nt < 4; nt++) {
                int col = n0 + nt * 16 + lrow;
                C[(size_t)row * HH + col] = acc[mt][nt][r];
            }
        }
}

// ---------------- host launch ----------------
extern "C" void kernel_launch(void* const* d_in, const int* in_sizes, int n_in,
                              void* d_out, int out_size, void* d_ws, size_t ws_size,
                              hipStream_t stream) {
    const float* hidden = (const float*)d_in[0];
    const float* maskp  = (const float*)d_in[1];
    const float* cosT   = (const float*)d_in[2];
    const float* sinT   = (const float*)d_in[3];
    const float* Wq     = (const float*)d_in[4];
    const float* Wk     = (const float*)d_in[5];
    const float* Wv     = (const float*)d_in[6];
    const float* Wo     = (const float*)d_in[7];
    float* out = (float*)d_out;

    char* ws = (char*)d_ws;
    auto alloc = [&](size_t bytes) {
        char* p = ws;
        ws += (bytes + 255) & ~(size_t)255;
        return p;
    };
    const size_t XB = (size_t)MM * HH * sizeof(short);  // 16.78 MB
    const size_t WB = (size_t)HH * HH * sizeof(short);  //  8.39 MB
    short* Xh  = (short*)alloc(XB);
    short* Wqh = (short*)alloc(WB);
    short* Wkh = (short*)alloc(WB);
    short* Wvh = (short*)alloc(WB);
    short* Woh = (short*)alloc(WB);
    short* Wol = (short*)alloc(WB);
    short* Qr  = (short*)alloc(XB);
    short* Kr  = (short*)alloc(XB);
    short* Vt  = (short*)alloc(XB);
    short* Ah  = (short*)alloc(XB);
    short* Al  = (short*)alloc(XB);

    const int nAll = N4X + 4 * N4W;   // 6291456 float4 items
    k_cvt_all<<<dim3(nAll / 256), dim3(256), 0, stream>>>(
        hidden, Wq, Wk, Wv, Wo, Xh, Wqh, Wkh, Wvh, Woh, Wol);

    k_gemm_qkv<<<dim3(HH / 128, MM / 128), dim3(256), 0, stream>>>(
        Xh, Wqh, Wkh, Wvh, cosT, sinT, Qr, Kr, Vt);

    k_attn<<<dim3(NB * NHH, SS / 256), dim3(256), 0, stream>>>(
        Qr, Kr, Vt, maskp, Ah, Al);

    k_gemm_wo<<<dim3(HH / 128, MM / 128), dim3(256), 0, stream>>>(
        Ah, Al, Woh, Wol, out);
}

// Round 10
// 398.104 us; speedup vs baseline: 1.4454x; 1.4454x over previous
//
#include <hip/hip_runtime.h>
#include <stdint.h>
#include <math.h>

#define NB 2
#define SS 2048
#define HH 2048
#define NHH 32
#define HDD 64
#define MM (NB*SS)   // 4096

typedef __attribute__((ext_vector_type(8))) short short8;
typedef __attribute__((ext_vector_type(4))) short short4v;
typedef __attribute__((ext_vector_type(4))) float f32x4;

#define GLOBAL_AS const __attribute__((address_space(1))) void*
#define LDS_AS __attribute__((address_space(3))) void*

static __device__ __forceinline__ short rne_bf16(float x) {
    uint32_t u = __builtin_bit_cast(uint32_t, x);
    u += 0x7FFFu + ((u >> 16) & 1u);
    return (short)(u >> 16);
}
static __device__ __forceinline__ float bf16f(short h) {
    return __builtin_bit_cast(float, (uint32_t)((uint16_t)h) << 16);
}
// HW packed f32->bf16 (RNE), gfx950: lo16 = bf16(a), hi16 = bf16(b)
static __device__ __forceinline__ uint32_t cvt_pk_bf16(float a, float b) {
    uint32_t r;
    asm("v_cvt_pk_bf16_f32 %0, %1, %2" : "=v"(r) : "v"(a), "v"(b));
    return r;
}
static __device__ __forceinline__ float fast_exp2(float x) {
    float r;
    asm("v_exp_f32 %0, %1" : "=v"(r) : "v"(x));
    return r;
}

// ---------------- fused convert: X, Wq, Wk, Wv (plain) + Wo (split) ----------------
// One launch instead of five (removes 4 launch gaps; work is ~22 us total).
#define N4X  2097152   // MM*HH/4
#define N4W  1048576   // HH*HH/4
__global__ void __launch_bounds__(256)
k_cvt_all(const float* __restrict__ X, const float* __restrict__ Wq,
          const float* __restrict__ Wk, const float* __restrict__ Wv,
          const float* __restrict__ Wo,
          short* __restrict__ Xh, short* __restrict__ Wqh, short* __restrict__ Wkh,
          short* __restrict__ Wvh, short* __restrict__ Woh, short* __restrict__ Wol)
{
    int i = blockIdx.x * blockDim.x + threadIdx.x;
    const float* src;
    short* dst;
    int j = i;
    if (i < N4X)                { src = X;  dst = Xh;  }
    else if (i < N4X + N4W)     { src = Wq; dst = Wqh; j = i - N4X; }
    else if (i < N4X + 2*N4W)   { src = Wk; dst = Wkh; j = i - N4X - N4W; }
    else if (i < N4X + 3*N4W)   { src = Wv; dst = Wvh; j = i - N4X - 2*N4W; }
    else {
        j = i - N4X - 3*N4W;
        float4 f = reinterpret_cast<const float4*>(Wo)[j];
        short4v h, l;
        h.x = rne_bf16(f.x); l.x = rne_bf16(f.x - bf16f(h.x));
        h.y = rne_bf16(f.y); l.y = rne_bf16(f.y - bf16f(h.y));
        h.z = rne_bf16(f.z); l.z = rne_bf16(f.z - bf16f(h.z));
        h.w = rne_bf16(f.w); l.w = rne_bf16(f.w - bf16f(h.w));
        reinterpret_cast<short4v*>(Woh)[j] = h;
        reinterpret_cast<short4v*>(Wol)[j] = l;
        return;
    }
    float4 f = reinterpret_cast<const float4*>(src)[j];
    short4v o;
    o.x = rne_bf16(f.x); o.y = rne_bf16(f.y);
    o.z = rne_bf16(f.z); o.w = rne_bf16(f.w);
    reinterpret_cast<short4v*>(dst)[j] = o;
}

// ---------------- fused QKV projection GEMM + RoPE ----------------
// Round-4 verified optimum of the 128^2/2-phase family (96.7us, MfmaUtil 45.6,
// BANK_CONFLICT 0): BK=64, T2 XOR-swizzled LDS (source pre-swizzle + swizzled
// read), T1 XCD-chunked block remap. Restructuring attempts (dbuf drain/counted
// vmcnt, direct-L2 B) all regressed — see session ledger rounds 5/6/9.
__global__ void __launch_bounds__(256, 2)
k_gemm_qkv(const short* __restrict__ X,
           const short* __restrict__ Wqh, const short* __restrict__ Wkh, const short* __restrict__ Wvh,
           const float* __restrict__ cosT, const float* __restrict__ sinT,
           short* __restrict__ Qr, short* __restrict__ Kr, short* __restrict__ Vt)
{
    __shared__ short lA[128 * 64];
    __shared__ short lBq[128 * 64];
    __shared__ short lBk[128 * 64];
    __shared__ short lBv[128 * 64];
    const int tid = threadIdx.x;
    const int lane = tid & 63;
    const int wave = tid >> 6;
    const int lrow = lane & 15;
    const int quad = lane >> 4;
    const int swz = lrow & 7;

    // XCD-chunked remap: lin%8 = XCD; each XCD gets nblk in {2x,2x+1} x all mblk
    const int lin = blockIdx.y * 16 + blockIdx.x;   // grid (16,32)
    const int pos = lin >> 3;
    const int nblk = ((lin & 7) * 2 + (pos & 1)) * 128;
    const int mblk = (pos >> 1) * 128;
    const int m0 = mblk + (wave >> 1) * 64;
    const int n0 = nblk + (wave & 1) * 64;
    const int mw = (wave >> 1) * 64;
    const int nw = (wave & 1) * 64;

    // staging: wave w, call j covers rows w*32 + j*8 + (lane>>3);
    // 16B chunk (lane&7)^(lane>>3) of the 128B row (inverse swizzle at source).
    const int srow = wave * 32 + (lane >> 3);
    const int skc = ((lane & 7) ^ (lane >> 3)) * 8;
    const short* gA = X   + (size_t)(mblk + srow) * HH + skc;
    const short* gQ = Wqh + (size_t)(nblk + srow) * HH + skc;
    const short* gK = Wkh + (size_t)(nblk + srow) * HH + skc;
    const short* gV = Wvh + (size_t)(nblk + srow) * HH + skc;
    const int lofs = wave * 2048;

    f32x4 acc[3][4][4];
    #pragma unroll
    for (int z = 0; z < 3; z++)
        #pragma unroll
        for (int i = 0; i < 4; i++)
            #pragma unroll
            for (int j = 0; j < 4; j++) acc[z][i][j] = 0.f;

    #pragma unroll 1
    for (int k0 = 0; k0 < HH; k0 += 64) {
        __syncthreads();
        #pragma unroll
        for (int j = 0; j < 4; j++) {
            size_t go = (size_t)j * 8 * HH + k0;
            int lo = lofs + j * 512;
            __builtin_amdgcn_global_load_lds((GLOBAL_AS)(gA + go), (LDS_AS)(&lA[lo]),  16, 0, 0);
            __builtin_amdgcn_global_load_lds((GLOBAL_AS)(gQ + go), (LDS_AS)(&lBq[lo]), 16, 0, 0);
            __builtin_amdgcn_global_load_lds((GLOBAL_AS)(gK + go), (LDS_AS)(&lBk[lo]), 16, 0, 0);
            __builtin_amdgcn_global_load_lds((GLOBAL_AS)(gV + go), (LDS_AS)(&lBv[lo]), 16, 0, 0);
        }
        __syncthreads();

        const short* lBz[3] = { lBq, lBk, lBv };
        #pragma unroll
        for (int kk = 0; kk < 2; kk++) {
            const int csl = ((kk * 4 + quad) ^ swz) * 8;
            short8 a[4];
            #pragma unroll
            for (int mt = 0; mt < 4; mt++)
                a[mt] = *reinterpret_cast<const short8*>(&lA[(mw + mt * 16 + lrow) * 64 + csl]);
            #pragma unroll
            for (int z = 0; z < 3; z++) {
                short8 b[4];
                #pragma unroll
                for (int nt = 0; nt < 4; nt++)
                    b[nt] = *reinterpret_cast<const short8*>(&lBz[z][(nw + nt * 16 + lrow) * 64 + csl]);
                #pragma unroll
                for (int mt = 0; mt < 4; mt++)
                    #pragma unroll
                    for (int nt = 0; nt < 4; nt++)
                        acc[z][mt][nt] = __builtin_amdgcn_mfma_f32_16x16x32_bf16(a[mt], b[nt], acc[z][mt][nt], 0, 0, 0);
            }
        }
    }

    const float QSCL = 0.18033688011112042f;  // log2(e)/sqrt(HD)

    #pragma unroll
    for (int z = 0; z < 3; z++) {
        #pragma unroll
        for (int mt = 0; mt < 4; mt++) {
            #pragma unroll
            for (int r = 0; r < 4; r++) {
                int row = m0 + mt * 16 + quad * 4 + r;   // global m = b*S + s
                int b_i = row >> 11;
                int s_i = row & (SS - 1);
                #pragma unroll
                for (int nt = 0; nt < 4; nt++) {
                    int col = n0 + nt * 16 + lrow;       // global n = h*64 + d
                    int h_i = col >> 6;
                    int d_i = col & 63;
                    float v = acc[z][mt][nt][r];
                    if (z < 2) {
                        float pair = (nt & 2) ? acc[z][mt][nt - 2][r] : -acc[z][mt][nt + 2][r];
                        float c = cosT[s_i * HDD + d_i];
                        float sn = sinT[s_i * HDD + d_i];
                        v = v * c + pair * sn;
                        if (z == 0) v *= QSCL;
                        short* dst = (z == 0) ? Qr : Kr;
                        dst[(((size_t)b_i * NHH + h_i) * SS + s_i) * HDD + d_i] = rne_bf16(v);
                    } else {
                        Vt[(((size_t)b_i * NHH + h_i) * HDD + d_i) * SS + s_i] = rne_bf16(v);
                    }
                }
            }
        }
    }
}

// ---------------- flash attention: S^T MFMA + fixed-max softmax ----------------
// (round-4 version: LDS-shared K/V dbuf, cvt_pk pack, MFMA-ones denom)
__global__ void __launch_bounds__(256, 2)
k_attn(const short* __restrict__ Qr, const short* __restrict__ Kr, const short* __restrict__ Vt,
       const float* __restrict__ mask,
       short* __restrict__ Ah, short* __restrict__ Al)
{
    __shared__ short plds[4][4096];    // 32 KB: per-wave P scratch (swizzled)
    __shared__ short ldsK[2][4096];    // 16 KB: K tile dbuf, 64 rows x 64 d, xor-swizzled
    __shared__ short ldsV[2][4096];    // 16 KB: V tile dbuf, 64 d x 64 k, xor-swizzled
    const int lane = threadIdx.x & 63;
    const int wave = threadIdx.x >> 6;
    const int lrow = lane & 15;
    const int quad = lane >> 4;
    const int aofs = lrow & 7;
    const int b = blockIdx.x >> 5;
    const int h = blockIdx.x & 31;
    const int q0w = blockIdx.y * 256 + wave * 64;

    const size_t bh = (size_t)b * NHH + h;
    const short* Qbase = Qr + bh * SS * HDD;
    const short* Kbase = Kr + bh * SS * HDD;
    const short* Vbase = Vt + bh * (size_t)HDD * SS;
    const float* mrow = mask + b * SS;
    char* cb = (char*)&plds[wave][0];

    const int strow = lane >> 3;                 // 0..7
    const int stch  = (lane & 7) ^ strow;        // pre-swizzled chunk
    const short* Kst0 = Kbase + (size_t)(wave * 16 + strow)     * HDD + stch * 8;
    const short* Kst1 = Kbase + (size_t)(wave * 16 + 8 + strow) * HDD + stch * 8;
    const short* Vst0 = Vbase + (size_t)(wave * 16 + strow)     * SS  + stch * 8;
    const short* Vst1 = Vbase + (size_t)(wave * 16 + 8 + strow) * SS  + stch * 8;
    const int ldst0 = wave * 1024;       // shorts: rows w*16 .. w*16+7
    const int ldst1 = wave * 1024 + 512; // shorts: rows w*16+8 .. w*16+15

#define STAGE_KV(buf, kk) do { \
    __builtin_amdgcn_global_load_lds((GLOBAL_AS)(Kst0 + (size_t)(kk) * HDD), (LDS_AS)(&ldsK[buf][ldst0]), 16, 0, 0); \
    __builtin_amdgcn_global_load_lds((GLOBAL_AS)(Kst1 + (size_t)(kk) * HDD), (LDS_AS)(&ldsK[buf][ldst1]), 16, 0, 0); \
    __builtin_amdgcn_global_load_lds((GLOBAL_AS)(Vst0 + (kk)), (LDS_AS)(&ldsV[buf][ldst0]), 16, 0, 0); \
    __builtin_amdgcn_global_load_lds((GLOBAL_AS)(Vst1 + (kk)), (LDS_AS)(&ldsV[buf][ldst1]), 16, 0, 0); \
} while (0)

    short8 qf[4][2];
    #pragma unroll
    for (int nt = 0; nt < 4; nt++)
        #pragma unroll
        for (int c = 0; c < 2; c++)
            qf[nt][c] = *reinterpret_cast<const short8*>(
                Qbase + (size_t)(q0w + nt * 16 + lrow) * HDD + c * 32 + quad * 8);

    short8 onesf;
    #pragma unroll
    for (int i = 0; i < 8; i++) onesf[i] = (short)0x3F80;   // bf16 1.0

    f32x4 oacc[4][4];
    f32x4 lacc[4];
    #pragma unroll
    for (int i = 0; i < 4; i++) {
        lacc[i] = 0.f;
        #pragma unroll
        for (int j = 0; j < 4; j++) oacc[i][j] = 0.f;
    }

    const float L2E = 1.44269504f;

    // prologue: stage tile 0
    STAGE_KV(0, 0);
    asm volatile("s_waitcnt vmcnt(0)" ::: "memory");
    __syncthreads();

    int cur = 0;
    #pragma unroll 1
    for (int k0 = 0; k0 < SS; k0 += 64) {
        if (k0 + 64 < SS) STAGE_KV(cur ^ 1, k0 + 64);

        short8 kf[4][2];
        #pragma unroll
        for (int kt = 0; kt < 4; kt++)
            #pragma unroll
            for (int c = 0; c < 2; c++)
                kf[kt][c] = *reinterpret_cast<const short8*>(
                    &ldsK[cur][(kt * 16 + lrow) * 64 + (((4 * c + quad) ^ aofs) * 8)]);

        f32x4 sacc[4][4];
        #pragma unroll
        for (int kt = 0; kt < 4; kt++)
            #pragma unroll
            for (int nt = 0; nt < 4; nt++) {
                f32x4 z4 = 0.f;
                z4 = __builtin_amdgcn_mfma_f32_16x16x32_bf16(kf[kt][0], qf[nt][0], z4, 0, 0, 0);
                sacc[kt][nt] = __builtin_amdgcn_mfma_f32_16x16x32_bf16(kf[kt][1], qf[nt][1], z4, 0, 0, 0);
            }

        asm volatile("s_waitcnt lgkmcnt(0)" ::: "memory");

        #pragma unroll
        for (int kt = 0; kt < 4; kt++) {
            float4 mk = *reinterpret_cast<const float4*>(mrow + k0 + kt * 16 + quad * 4);
            float m0v = mk.x * L2E, m1v = mk.y * L2E, m2v = mk.z * L2E, m3v = mk.w * L2E;
            #pragma unroll
            for (int nt = 0; nt < 4; nt++) {
                float p0 = fast_exp2(sacc[kt][nt][0] + m0v);
                float p1 = fast_exp2(sacc[kt][nt][1] + m1v);
                float p2 = fast_exp2(sacc[kt][nt][2] + m2v);
                float p3 = fast_exp2(sacc[kt][nt][3] + m3v);
                uint2 w;
                w.x = cvt_pk_bf16(p0, p1);
                w.y = cvt_pk_bf16(p2, p3);
                *reinterpret_cast<uint2*>(
                    cb + (nt * 16 + lrow) * 128 +
                    (((2 * kt + (quad >> 1)) ^ aofs) * 16) + (quad & 1) * 8) = w;
            }
        }

        asm volatile("s_waitcnt lgkmcnt(0)" ::: "memory");

        #pragma unroll
        for (int c = 0; c < 2; c++) {
            short8 pf[4], vf[4];
            #pragma unroll
            for (int mt = 0; mt < 4; mt++)
                pf[mt] = *reinterpret_cast<const short8*>(
                    cb + (mt * 16 + lrow) * 128 + (((4 * c + quad) ^ aofs) * 16));
            #pragma unroll
            for (int dt = 0; dt < 4; dt++)
                vf[dt] = *reinterpret_cast<const short8*>(
                    &ldsV[cur][(dt * 16 + lrow) * 64 + (((4 * c + quad) ^ aofs) * 8)]);
            #pragma unroll
            for (int mt = 0; mt < 4; mt++) {
                lacc[mt] = __builtin_amdgcn_mfma_f32_16x16x32_bf16(pf[mt], onesf, lacc[mt], 0, 0, 0);
                #pragma unroll
                for (int dt = 0; dt < 4; dt++)
                    oacc[mt][dt] = __builtin_amdgcn_mfma_f32_16x16x32_bf16(pf[mt], vf[dt], oacc[mt][dt], 0, 0, 0);
            }
        }

        asm volatile("s_waitcnt vmcnt(0)" ::: "memory");
        __syncthreads();
        cur ^= 1;
    }
#undef STAGE_KV

    float linv[4][4];
    #pragma unroll
    for (int mt = 0; mt < 4; mt++)
        #pragma unroll
        for (int r = 0; r < 4; r++)
            linv[mt][r] = 1.f / lacc[mt][r];

    #pragma unroll
    for (int mt = 0; mt < 4; mt++) {
        #pragma unroll
        for (int r = 0; r < 4; r++) {
            int s_i = q0w + mt * 16 + quad * 4 + r;
            size_t row = (size_t)b * SS + s_i;
            #pragma unroll
            for (int dt = 0; dt < 4; dt++) {
                float x = oacc[mt][dt][r] * linv[mt][r];
                short hi = rne_bf16(x);
                short lo = rne_bf16(x - bf16f(hi));
                size_t idx = row * HH + (size_t)h * 64 + dt * 16 + lrow;
                Ah[idx] = hi;
                Al[idx] = lo;
            }
        }
    }
}

// ---------------- output projection GEMM, split-bf16 (3-term), LDS staged ----------------
// Round-4 verified version: BK=64 + T2 swizzle + T1 XCD-chunked remap.
__global__ void __launch_bounds__(256, 2)
k_gemm_wo(const short* __restrict__ Ahh, const short* __restrict__ All,
          const short* __restrict__ Bhh, const short* __restrict__ Bll,
          float* __restrict__ C)
{
    __shared__ short lAh[128 * 64];
    __shared__ short lAl[128 * 64];
    __shared__ short lBh[128 * 64];
    __shared__ short lBl[128 * 64];
    const int tid = threadIdx.x;
    const int lane = tid & 63;
    const int wave = tid >> 6;
    const int lrow = lane & 15;
    const int quad = lane >> 4;
    const int swz = lrow & 7;

    const int lin = blockIdx.y * 16 + blockIdx.x;   // grid (16,32)
    const int pos = lin >> 3;
    const int nblk = ((lin & 7) * 2 + (pos & 1)) * 128;
    const int mblk = (pos >> 1) * 128;
    const int m0 = mblk + (wave >> 1) * 64;
    const int n0 = nblk + (wave & 1) * 64;
    const int mw = (wave >> 1) * 64;
    const int nw = (wave & 1) * 64;

    const int srow = wave * 32 + (lane >> 3);
    const int skc = ((lane & 7) ^ (lane >> 3)) * 8;
    const short* gAh = Ahh + (size_t)(mblk + srow) * HH + skc;
    const short* gAl = All + (size_t)(mblk + srow) * HH + skc;
    const short* gBh = Bhh + (size_t)(nblk + srow) * HH + skc;
    const short* gBl = Bll + (size_t)(nblk + srow) * HH + skc;
    short* lAhw = &lAh[wave * 2048];
    short* lAlw = &lAl[wave * 2048];
    short* lBhw = &lBh[wave * 2048];
    short* lBlw = &lBl[wave * 2048];

    f32x4 acc[4][4];
    #pragma unroll
    for (int i = 0; i < 4; i++)
        #pragma unroll
        for (int j = 0; j < 4; j++) acc[i][j] = 0.f;

    #pragma unroll 1
    for (int k0 = 0; k0 < HH; k0 += 64) {
        __syncthreads();
        #pragma unroll
        for (int j = 0; j < 4; j++) {
            size_t go = (size_t)j * 8 * HH + k0;
            __builtin_amdgcn_global_load_lds((GLOBAL_AS)(gAh + go), (LDS_AS)(lAhw + j * 512), 16, 0, 0);
            __builtin_amdgcn_global_load_lds((GLOBAL_AS)(gAl + go), (LDS_AS)(lAlw + j * 512), 16, 0, 0);
            __builtin_amdgcn_global_load_lds((GLOBAL_AS)(gBh + go), (LDS_AS)(lBhw + j * 512), 16, 0, 0);
            __builtin_amdgcn_global_load_lds((GLOBAL_AS)(gBl + go), (LDS_AS)(lBlw + j * 512), 16, 0, 0);
        }
        __syncthreads();

        #pragma unroll
        for (int kk = 0; kk < 2; kk++) {
            const int csl = ((kk * 4 + quad) ^ swz) * 8;
            short8 ah[4], al[4], bh[4], bl[4];
            #pragma unroll
            for (int mt = 0; mt < 4; mt++) {
                int off = (mw + mt * 16 + lrow) * 64 + csl;
                ah[mt] = *reinterpret_cast<const short8*>(&lAh[off]);
                al[mt] = *reinterpret_cast<const short8*>(&lAl[off]);
            }
            #pragma unroll
            for (int nt = 0; nt < 4; nt++) {
                int off = (nw + nt * 16 + lrow) * 64 + csl;
                bh[nt] = *reinterpret_cast<const short8*>(&lBh[off]);
                bl[nt] = *reinterpret_cast<const short8*>(&lBl[off]);
            }
            #pragma unroll
            for (int mt = 0; mt < 4; mt++)
                #pragma unroll
                for (int nt = 0; nt < 4; nt++) {
                    acc[mt][nt] = __builtin_amdgcn_mfma_f32_16x16x32_bf16(ah[mt], bh[nt], acc[mt][nt], 0, 0, 0);
                    acc[mt][nt] = __builtin_amdgcn_mfma_f32_16x16x32_bf16(al[mt], bh[nt], acc[mt][nt], 0, 0, 0);
                    acc[mt][nt] = __builtin_amdgcn_mfma_f32_16x16x32_bf16(ah[mt], bl[nt], acc[mt][nt], 0, 0, 0);
                }
        }
    }

    #pragma unroll
    for (int mt = 0; mt < 4; mt++)
        #pragma unroll
        for (int r = 0; r < 4; r++) {
            int row = m0 + mt * 16 + quad * 4 + r;
            #pragma unroll
            for (int nt = 0; nt < 4; nt++) {
                int col = n0 + nt * 16 + lrow;
                C[(size_t)row * HH + col] = acc[mt][nt][r];
            }
        }
}

// ---------------- host launch ----------------
extern "C" void kernel_launch(void* const* d_in, const int* in_sizes, int n_in,
                              void* d_out, int out_size, void* d_ws, size_t ws_size,
                              hipStream_t stream) {
    const float* hidden = (const float*)d_in[0];
    const float* maskp  = (const float*)d_in[1];
    const float* cosT   = (const float*)d_in[2];
    const float* sinT   = (const float*)d_in[3];
    const float* Wq     = (const float*)d_in[4];
    const float* Wk     = (const float*)d_in[5];
    const float* Wv     = (const float*)d_in[6];
    const float* Wo     = (const float*)d_in[7];
    float* out = (float*)d_out;

    char* ws = (char*)d_ws;
    auto alloc = [&](size_t bytes) {
        char* p = ws;
        ws += (bytes + 255) & ~(size_t)255;
        return p;
    };
    const size_t XB = (size_t)MM * HH * sizeof(short);  // 16.78 MB
    const size_t WB = (size_t)HH * HH * sizeof(short);  //  8.39 MB
    short* Xh  = (short*)alloc(XB);
    short* Wqh = (short*)alloc(WB);
    short* Wkh = (short*)alloc(WB);
    short* Wvh = (short*)alloc(WB);
    short* Woh = (short*)alloc(WB);
    short* Wol = (short*)alloc(WB);
    short* Qr  = (short*)alloc(XB);
    short* Kr  = (short*)alloc(XB);
    short* Vt  = (short*)alloc(XB);
    short* Ah  = (short*)alloc(XB);
    short* Al  = (short*)alloc(XB);

    const int nAll = N4X + 4 * N4W;   // 6291456 float4 items
    k_cvt_all<<<dim3(nAll / 256), dim3(256), 0, stream>>>(
        hidden, Wq, Wk, Wv, Wo, Xh, Wqh, Wkh, Wvh, Woh, Wol);

    k_gemm_qkv<<<dim3(HH / 128, MM / 128), dim3(256), 0, stream>>>(
        Xh, Wqh, Wkh, Wvh, cosT, sinT, Qr, Kr, Vt);

    k_attn<<<dim3(NB * NHH, SS / 256), dim3(256), 0, stream>>>(
        Qr, Kr, Vt, maskp, Ah, Al);

    k_gemm_wo<<<dim3(HH / 128, MM / 128), dim3(256), 0, stream>>>(
        Ah, Al, Woh, Wol, out);
}